// Round 8
// baseline (581.166 us; speedup 1.0000x reference)
//
#include <hip/hip_runtime.h>
#include <hip/hip_bf16.h>

#define N_NODES 10000
#define N_EDGES 320000
#define D 128
#define NBINS 10000
#define NCHUNKS 2500
#define EDGE_GRID 1256   // multiple of 8 so grid-stride preserves chunk%8 (XCD swizzle)

typedef float f32x4 __attribute__((ext_vector_type(4)));
typedef float f32x2 __attribute__((ext_vector_type(2)));
typedef short bf16x8 __attribute__((ext_vector_type(8)));
typedef short bf16x16 __attribute__((ext_vector_type(16)));

static __device__ inline short f2bf(float f) {
    union { __hip_bfloat16 h; short s; } u;
    u.h = __float2bfloat16(f);
    return u.s;
}

static __device__ inline float bf2f(short s) {
    union { float f; unsigned u; } x;
    x.u = ((unsigned)(unsigned short)s) << 16;
    return x.f;
}

static __device__ inline float fast_rcp(float x) { return __builtin_amdgcn_rcpf(x); }

// Fused: blocks [0,1250) histogram dst; blocks [1250,1634) prepack all 5 weights.
// Pack order: out[((t*8+jt)*64+l)*8+b] = Wcat[32t + (l>>4)*8 + b][jt*16 + (l&15)]
__global__ void prep_hist(const float* __restrict__ W_sg, const float* __restrict__ W_tp,
                          const float* __restrict__ W_dg, const float* __restrict__ W_du,
                          const float* __restrict__ W_su, const float* __restrict__ W_eg,
                          short* __restrict__ Wsrc, short* __restrict__ Wdg,
                          short* __restrict__ Wdu, short* __restrict__ Wsu,
                          short* __restrict__ Weg,
                          const int* __restrict__ dst, int* __restrict__ cnt) {
    int bid = blockIdx.x;
    if (bid < 1250) {
        int i = bid * 256 + threadIdx.x;   // 1250*256 == N_EDGES exactly
        atomicAdd(&cnt[dst[i]], 1);
        return;
    }
    int idx = (bid - 1250) * 256 + threadIdx.x;
    const float* W0; const float* W1; short* out; int i2;
    if (idx < 32768)      { W0 = W_sg; W1 = W_tp; out = Wsrc; i2 = idx; }
    else if (idx < 49152) { W0 = W_dg; W1 = W_dg; out = Wdg;  i2 = idx - 32768; }
    else if (idx < 65536) { W0 = W_du; W1 = W_du; out = Wdu;  i2 = idx - 49152; }
    else if (idx < 81920) { W0 = W_su; W1 = W_su; out = Wsu;  i2 = idx - 65536; }
    else                  { W0 = W_eg; W1 = W_eg; out = Weg;  i2 = idx - 81920; }
    int b  = i2 & 7;
    int l  = (i2 >> 3) & 63;
    int jt = (i2 >> 9) & 7;
    int t  = i2 >> 12;
    int k = 32 * t + ((l >> 4) * 8) + b;
    int j = jt * 16 + (l & 15);
    float v = (k < 128) ? W0[k * 128 + j] : W1[(k - 128) * 128 + j];
    out[i2] = f2bf(v);
}

__launch_bounds__(1024)
__global__ void scan_kernel(const int* __restrict__ cnt, int* __restrict__ cursor) {
    __shared__ int s[1024];
    int t = threadIdx.x;
    int b0 = t * 10;
    int loc[10];
    int tot = 0;
#pragma unroll
    for (int i = 0; i < 10; ++i) {
        int v = (b0 + i < NBINS) ? cnt[b0 + i] : 0;
        loc[i] = tot; tot += v;
    }
    s[t] = tot;
    __syncthreads();
    for (int off = 1; off < 1024; off <<= 1) {
        int v = (t >= off) ? s[t - off] : 0;
        __syncthreads();
        s[t] += v;
        __syncthreads();
    }
    int base = (t == 0) ? 0 : s[t - 1];
#pragma unroll
    for (int i = 0; i < 10; ++i)
        if (b0 + i < NBINS) cursor[b0 + i] = base + loc[i];
}

__global__ void scatter_kernel(const int* __restrict__ src, const int* __restrict__ dst,
                               int* __restrict__ cursor,
                               int* __restrict__ perm,
                               int* __restrict__ src_s, int* __restrict__ dst_s) {
    int i = blockIdx.x * 256 + threadIdx.x;
    if (i < N_EDGES) {
        int d = dst[i];
        int p = atomicAdd(&cursor[d], 1);
        perm[p] = i;
        src_s[p] = src[i];
        dst_s[p] = d;
    }
}

// Unified: all four GEMMs for a 64-row stripe in one block (spk lines written whole).
__launch_bounds__(256)
__global__ void node_proj_kernel(const float* __restrict__ node,
                                 const float* __restrict__ timef,
                                 const short* __restrict__ Wsrc_pk,  // K=256 (W_sg ; W_tp)
                                 const short* __restrict__ Wdg_pk,
                                 const short* __restrict__ Wdu_pk,
                                 const short* __restrict__ Wsu_pk,
                                 const float* __restrict__ b_sg, const float* __restrict__ b_tp,
                                 const float* __restrict__ b_dg, const float* __restrict__ b_du,
                                 const float* __restrict__ b_su, const float* __restrict__ b_eg,
                                 short* __restrict__ spk,   // [N][256] bf16: per-lane {es8|bh8}
                                 short* __restrict__ dpk,   // [N][128] bf16 col-permuted: e_dst
                                 float* __restrict__ xs) {
    int tid = threadIdx.x;
    int w = tid >> 6;
    int l = tid & 63;
    int g = l >> 4;
    int lr = l & 15;
    int r0 = blockIdx.x * 64 + w * 16;
    int arow = r0 + lr;

    bf16x8 aN[4], aT[4];
    if (arow < N_NODES) {
        const float* np = node + (size_t)arow * D;
        const float* tp = timef + (size_t)arow * D;
#pragma unroll
        for (int t = 0; t < 4; ++t) {
            int k0 = 32 * t + g * 8;
            f32x4 v0 = *(const f32x4*)(np + k0);
            f32x4 v1 = *(const f32x4*)(np + k0 + 4);
            f32x4 u0 = *(const f32x4*)(tp + k0);
            f32x4 u1 = *(const f32x4*)(tp + k0 + 4);
            bf16x8 a, b;
#pragma unroll
            for (int i = 0; i < 4; ++i) {
                a[i] = f2bf(v0[i]); a[4 + i] = f2bf(v1[i]);
                b[i] = f2bf(u0[i]); b[4 + i] = f2bf(u1[i]);
            }
            aN[t] = a; aT[t] = b;
        }
    } else {
        bf16x8 z = {0, 0, 0, 0, 0, 0, 0, 0};
#pragma unroll
        for (int t = 0; t < 4; ++t) { aN[t] = z; aT[t] = z; }
    }

    const bf16x8* Bsrc = (const bf16x8*)Wsrc_pk;
    const bf16x8* Bdg  = (const bf16x8*)Wdg_pk;
    const bf16x8* Bdu  = (const bf16x8*)Wdu_pk;
    const bf16x8* Bsu  = (const bf16x8*)Wsu_pk;

    // e_src = node@W_sg + time@W_tp + biases   (K = 256) -> spk[row][lr*16 .. +8)
    {
        bf16x8 chunk[4];
#pragma unroll
        for (int jt = 0; jt < 8; ++jt) {
            int c = jt * 16 + lr;
            f32x4 acc = {0.f, 0.f, 0.f, 0.f};
#pragma unroll
            for (int t = 0; t < 4; ++t)
                acc = __builtin_amdgcn_mfma_f32_16x16x32_bf16(aN[t], Bsrc[(t * 8 + jt) * 64 + l], acc, 0, 0, 0);
#pragma unroll
            for (int t = 0; t < 4; ++t)
                acc = __builtin_amdgcn_mfma_f32_16x16x32_bf16(aT[t], Bsrc[((4 + t) * 8 + jt) * 64 + l], acc, 0, 0, 0);
            float bias = b_sg[c] + b_tp[c];
#pragma unroll
            for (int r = 0; r < 4; ++r) chunk[r][jt] = f2bf(acc[r] + bias);
        }
#pragma unroll
        for (int r = 0; r < 4; ++r) {
            int row = r0 + g * 4 + r;
            if (row < N_NODES) *(bf16x8*)(spk + (size_t)row * 256 + lr * 16) = chunk[r];
        }
    }

    // e_dst (+b_dg+b_eg) -> dpk ; Bh (+b_du) -> spk[row][lr*16+8..+16) ; xs (+b_su) f32
    {
        bf16x8 chD[4], chH[4];
        float xsv[4][8];
#pragma unroll
        for (int jt = 0; jt < 8; ++jt) {
            int c = jt * 16 + lr;
            f32x4 a0 = {0.f, 0.f, 0.f, 0.f}, a1 = a0, a2 = a0;
#pragma unroll
            for (int t = 0; t < 4; ++t) {
                a0 = __builtin_amdgcn_mfma_f32_16x16x32_bf16(aN[t], Bdg[(t * 8 + jt) * 64 + l], a0, 0, 0, 0);
                a1 = __builtin_amdgcn_mfma_f32_16x16x32_bf16(aN[t], Bdu[(t * 8 + jt) * 64 + l], a1, 0, 0, 0);
                a2 = __builtin_amdgcn_mfma_f32_16x16x32_bf16(aN[t], Bsu[(t * 8 + jt) * 64 + l], a2, 0, 0, 0);
            }
            float bdgc = b_dg[c] + b_eg[c];
            float bdu = b_du[c], bsu = b_su[c];
#pragma unroll
            for (int r = 0; r < 4; ++r) {
                chD[r][jt] = f2bf(a0[r] + bdgc);
                chH[r][jt] = f2bf(a1[r] + bdu);
                xsv[r][jt] = a2[r] + bsu;
            }
        }
#pragma unroll
        for (int r = 0; r < 4; ++r) {
            int row = r0 + g * 4 + r;
            if (row < N_NODES) {
                *(bf16x8*)(dpk + (size_t)row * D + lr * 8) = chD[r];
                *(bf16x8*)(spk + (size_t)row * 256 + lr * 16 + 8) = chH[r];
#pragma unroll
                for (int jt = 0; jt < 8; ++jt)
                    xs[(size_t)row * D + jt * 16 + lr] = xsv[r][jt];
            }
        }
    }
}

// ---- persistent edge kernel: grid-stride over 2500 chunks of 128 edges ----
// Per chunk, each wave handles 2 tiles of 16 dst-sorted edges.

#define TILE_LOAD_IDX(S, E0) \
    const int pm##S = perm[(E0) + lr]; \
    const int sv##S = src_s[(E0) + lr]; \
    const int dv##S = dst_s[(E0) + lr]; \
    int eidx##S[4], sidx##S[4], didx##S[4]; \
    _Pragma("unroll") \
    for (int r = 0; r < 4; ++r) { \
        int qq = g * 4 + r; \
        eidx##S[r] = __shfl(pm##S, qq); \
        sidx##S[r] = __shfl(sv##S, qq); \
        didx##S[r] = __shfl(dv##S, qq); \
    } \
    const int df##S = __shfl(dv##S, 0); \
    const bool uni##S = (df##S == __shfl(dv##S, 15));

#define TILE_GATHER(S) \
    bf16x16 esbh##S[4]; bf16x8 edv##S[4]; \
    _Pragma("unroll") \
    for (int r = 0; r < 4; ++r) \
        esbh##S[r] = *(const bf16x16*)(spk + (size_t)sidx##S[r] * 256 + lr * 16); \
    edv##S[0] = *(const bf16x8*)(dpk + (size_t)didx##S[0] * D + lr * 8); \
    if (!uni##S) { \
        _Pragma("unroll") \
        for (int r = 1; r < 4; ++r) \
            edv##S[r] = *(const bf16x8*)(dpk + (size_t)didx##S[r] * D + lr * 8); \
    } else { edv##S[1] = edv##S[0]; edv##S[2] = edv##S[0]; edv##S[3] = edv##S[0]; }

#define TILE_AFRAG(S) \
    bf16x8 aE##S[4]; \
    { const float* ep = edgef + (size_t)pm##S * D; \
      _Pragma("unroll") \
      for (int t = 0; t < 4; ++t) { \
        int k0 = 32 * t + g * 8; \
        f32x4 v0 = *(const f32x4*)(ep + k0); \
        f32x4 v1 = *(const f32x4*)(ep + k0 + 4); \
        bf16x8 a; \
        _Pragma("unroll") \
        for (int i = 0; i < 4; ++i) { a[i] = f2bf(v0[i]); a[4 + i] = f2bf(v1[i]); } \
        aE##S[t] = a; } }

// DEFER=1: if comb, stash tile-0 sums in aS0/aH0 instead of atomics.
// ADDPREV=1: if comb, add stashed sums before the (single) atomic pair.
#define TILE_COMPUTE(S, DEFER, ADDPREV) \
    f32x4 acc##S[8]; \
    _Pragma("unroll") \
    for (int jt = 0; jt < 8; ++jt) { \
        f32x4 c4 = {0.f, 0.f, 0.f, 0.f}; \
        _Pragma("unroll") \
        for (int t = 0; t < 4; ++t) \
            c4 = __builtin_amdgcn_mfma_f32_16x16x32_bf16(aE##S[t], Bp[(t * 8 + jt) * 64 + l], c4, 0, 0, 0); \
        acc##S[jt] = c4; } \
    float sum##S[4] = {0.f, 0.f, 0.f, 0.f}, sq##S[4] = {0.f, 0.f, 0.f, 0.f}; \
    _Pragma("unroll") \
    for (int jt = 0; jt < 8; ++jt) { \
        int c = jt * 16 + lr; \
        float sg[4], bsg[4]; \
        _Pragma("unroll") \
        for (int r = 0; r < 4; ++r) { \
            float m = acc##S[jt][r] + bf2f(esbh##S[r][jt]) + bf2f(edv##S[r][jt]); \
            acc##S[jt][r] = m; \
            float s = fast_rcp(1.f + __expf(-m)); \
            sg[r] = s; bsg[r] = bf2f(esbh##S[r][8 + jt]) * s; \
            sum##S[r] += m; sq##S[r] += m * m; } \
        if (uni##S) { \
            float aS = (sg[0] + sg[1]) + (sg[2] + sg[3]); \
            float aH = (bsg[0] + bsg[1]) + (bsg[2] + bsg[3]); \
            aS += __shfl_xor(aS, 16); aH += __shfl_xor(aH, 16); \
            aS += __shfl_xor(aS, 32); aH += __shfl_xor(aH, 32); \
            if (DEFER && comb) { aS0[jt] = aS; aH0[jt] = aH; } \
            else { \
                if (ADDPREV && comb) { aS += aS0[jt]; aH += aH0[jt]; } \
                if (g == 0) { \
                    atomicAdd(&ss [(size_t)df##S * D + c], aS); \
                    atomicAdd(&ssh[(size_t)df##S * D + c], aH); } } \
        } else { \
            float aS = sg[0], aH = bsg[0]; \
            _Pragma("unroll") \
            for (int r = 1; r < 4; ++r) { \
                if (didx##S[r] == didx##S[r - 1]) { aS += sg[r]; aH += bsg[r]; } \
                else { \
                    atomicAdd(&ss [(size_t)didx##S[r - 1] * D + c], aS); \
                    atomicAdd(&ssh[(size_t)didx##S[r - 1] * D + c], aH); \
                    aS = sg[r]; aH = bsg[r]; } } \
            atomicAdd(&ss [(size_t)didx##S[3] * D + c], aS); \
            atomicAdd(&ssh[(size_t)didx##S[3] * D + c], aH); } }

#define TILE_EPILOGUE(S) \
    _Pragma("unroll") \
    for (int r = 0; r < 4; ++r) { \
        float s = sum##S[r], q = sq##S[r]; \
        _Pragma("unroll") \
        for (int mk = 1; mk < 16; mk <<= 1) { s += __shfl_xor(s, mk); q += __shfl_xor(q, mk); } \
        float mean = s * (1.f / D); \
        sum##S[r] = mean; \
        sq##S[r] = rsqrtf(q * (1.f / D) - mean * mean + 1e-5f); } \
    _Pragma("unroll") \
    for (int jt = 0; jt < 8; ++jt) { \
        int c = jt * 16 + lr; \
        float gc = ln_g[c], bc = ln_b[c]; \
        _Pragma("unroll") \
        for (int r = 0; r < 4; ++r) { \
            float v = (acc##S[jt][r] - sum##S[r]) * sq##S[r] * gc + bc; \
            float sl = v * fast_rcp(1.f + __expf(-v)); \
            size_t off = (size_t)eidx##S[r] * D + c; \
            y[off] = edgef[off] + sl; } }

__launch_bounds__(256, 4)
__global__ void edge_kernel(const float* __restrict__ edgef,
                            const int* __restrict__ perm,
                            const int* __restrict__ src_s, const int* __restrict__ dst_s,
                            const short* __restrict__ Weg_pk,
                            const short* __restrict__ spk,   // [N][256]: {es8|bh8} per lane
                            const short* __restrict__ dpk,   // [N][128]: e_dst
                            const float* __restrict__ ln_g, const float* __restrict__ ln_b,
                            float* __restrict__ ss, float* __restrict__ ssh,
                            float* __restrict__ y) {
    __shared__ short Bs[128 * 128];  // 32 KB: Weg B-fragments, staged ONCE per block
    {
        const bf16x8* gw = (const bf16x8*)Weg_pk;
        bf16x8* sw = (bf16x8*)Bs;
        for (int i = threadIdx.x; i < 2048; i += 256) sw[i] = gw[i];
    }
    __syncthreads();

    int tid = threadIdx.x;
    int w = tid >> 6;
    int l = tid & 63;
    int g = l >> 4;
    int lr = l & 15;
    const bf16x8* Bp = (const bf16x8*)Bs;

    // grid-stride over chunks; EDGE_GRID % 8 == 0 keeps chunk%8 == blockIdx%8
    for (int cc = blockIdx.x; cc < NCHUNKS; cc += EDGE_GRID) {
        // bijective XCD-chunked swizzle over 2500 chunks (q=312, r=4)
        int xcd = cc & 7, boff = cc >> 3;
        int swz = (xcd < 4 ? xcd * 313 : 1252 + (xcd - 4) * 312) + boff;
        int ebase = swz * 128 + w * 32;

        TILE_LOAD_IDX(0, ebase)
        TILE_LOAD_IDX(1, ebase + 16)
        const bool comb = uni0 && uni1 && (df0 == df1);  // whole 32-edge window one dst
        float aS0[8], aH0[8];

        TILE_GATHER(0)
        TILE_AFRAG(0)
        TILE_AFRAG(1)
        TILE_COMPUTE(0, 1, 0)
        TILE_GATHER(1)
        TILE_EPILOGUE(0)
        TILE_COMPUTE(1, 0, 1)
        TILE_EPILOGUE(1)
    }
}

__launch_bounds__(256)
__global__ void node_out_kernel(const float* __restrict__ node,
                                const float* __restrict__ xs,
                                const float* __restrict__ ssh, const float* __restrict__ ss,
                                const float* __restrict__ ln_g, const float* __restrict__ ln_b,
                                float* __restrict__ x) {
    int w = threadIdx.x >> 6;
    int l = threadIdx.x & 63;
    int row = blockIdx.x * 4 + w;
    if (row >= N_NODES) return;
    size_t base = (size_t)row * D + 2 * l;
    f32x2 xv = *(const f32x2*)(xs + base);
    f32x2 hs = *(const f32x2*)(ssh + base);
    f32x2 sv = *(const f32x2*)(ss + base);
    float v0 = xv[0] + hs[0] / (sv[0] + 1e-6f);
    float v1 = xv[1] + hs[1] / (sv[1] + 1e-6f);
    float s = v0 + v1, q = v0 * v0 + v1 * v1;
#pragma unroll
    for (int mk = 1; mk < 64; mk <<= 1) { s += __shfl_xor(s, mk); q += __shfl_xor(q, mk); }
    float mean = s * (1.f / D);
    float var = q * (1.f / D) - mean * mean;
    float rstd = rsqrtf(var + 1e-5f);
    float t0 = (v0 - mean) * rstd * ln_g[2 * l] + ln_b[2 * l];
    float t1 = (v1 - mean) * rstd * ln_g[2 * l + 1] + ln_b[2 * l + 1];
    t0 = t0 * fast_rcp(1.f + __expf(-t0));
    t1 = t1 * fast_rcp(1.f + __expf(-t1));
    f32x2 nv = *(const f32x2*)(node + base);
    f32x2 outv;
    outv[0] = nv[0] + t0;
    outv[1] = nv[1] + t1;
    *(f32x2*)(x + base) = outv;
}

extern "C" void kernel_launch(void* const* d_in, const int* in_sizes, int n_in,
                              void* d_out, int out_size, void* d_ws, size_t ws_size,
                              hipStream_t stream) {
    const float* node  = (const float*)d_in[0];
    const float* edgef = (const float*)d_in[1];
    const float* timef = (const float*)d_in[2];
    const int*   src   = (const int*)d_in[3];
    const int*   dst   = (const int*)d_in[4];
    const float* W_tp = (const float*)d_in[5];  const float* b_tp = (const float*)d_in[6];
    const float* W_sg = (const float*)d_in[7];  const float* b_sg = (const float*)d_in[8];
    const float* W_dg = (const float*)d_in[9];  const float* b_dg = (const float*)d_in[10];
    const float* W_eg = (const float*)d_in[11]; const float* b_eg = (const float*)d_in[12];
    const float* W_su = (const float*)d_in[13]; const float* b_su = (const float*)d_in[14];
    const float* W_du = (const float*)d_in[15]; const float* b_du = (const float*)d_in[16];
    const float* ln_e_g = (const float*)d_in[17]; const float* ln_e_b = (const float*)d_in[18];
    const float* ln_n_g = (const float*)d_in[19]; const float* ln_n_b = (const float*)d_in[20];

    char* ws = (char*)d_ws;
    size_t nd = (size_t)N_NODES * D;
    // cnt | cursor | ss | ssh contiguous -> single memset clears all
    int* cnt       = (int*)ws; ws += 10240 * 4;
    int* cursor    = (int*)ws; ws += 10240 * 4;
    float* ss    = (float*)ws; ws += nd * 4;
    float* ssh   = (float*)ws; ws += nd * 4;
    float* xs    = (float*)ws; ws += nd * 4;
    short* spk   = (short*)ws; ws += (size_t)N_NODES * 256 * 2;
    short* dpk   = (short*)ws; ws += nd * 2;
    short* Wsrc_pk = (short*)ws; ws += 256 * 128 * 2;
    short* Wdg_pk  = (short*)ws; ws += 128 * 128 * 2;
    short* Wdu_pk  = (short*)ws; ws += 128 * 128 * 2;
    short* Wsu_pk  = (short*)ws; ws += 128 * 128 * 2;
    short* Weg_pk  = (short*)ws; ws += 128 * 128 * 2;
    int* perm      = (int*)ws; ws += (size_t)N_EDGES * 4;
    int* src_s     = (int*)ws; ws += (size_t)N_EDGES * 4;
    int* dst_s     = (int*)ws; ws += (size_t)N_EDGES * 4;

    hipMemsetAsync(cnt, 0, 2 * 10240 * 4 + 2 * nd * 4, stream);

    // fused prepack + histogram
    prep_hist<<<1634, 256, 0, stream>>>(W_sg, W_tp, W_dg, W_du, W_su, W_eg,
                                        Wsrc_pk, Wdg_pk, Wdu_pk, Wsu_pk, Weg_pk,
                                        dst, cnt);
    scan_kernel<<<1, 1024, 0, stream>>>(cnt, cursor);
    scatter_kernel<<<(N_EDGES + 255) / 256, 256, 0, stream>>>(src, dst, cursor, perm, src_s, dst_s);

    node_proj_kernel<<<(N_NODES + 63) / 64, 256, 0, stream>>>(
        node, timef, Wsrc_pk, Wdg_pk, Wdu_pk, Wsu_pk,
        b_sg, b_tp, b_dg, b_du, b_su, b_eg, spk, dpk, xs);

    edge_kernel<<<EDGE_GRID, 256, 0, stream>>>(
        edgef, perm, src_s, dst_s, Weg_pk, spk, dpk,
        ln_e_g, ln_e_b, ss, ssh, (float*)d_out + nd);

    node_out_kernel<<<N_NODES / 4, 256, 0, stream>>>(
        node, xs, ssh, ss, ln_n_g, ln_n_b, (float*)d_out);
}

// Round 9
// 270.662 us; speedup vs baseline: 2.1472x; 2.1472x over previous
//
#include <hip/hip_runtime.h>
#include <hip/hip_bf16.h>

#define N_NODES 10000
#define N_EDGES 320000
#define D 128
#define NBINS 10000

typedef float f32x4 __attribute__((ext_vector_type(4)));
typedef float f32x2 __attribute__((ext_vector_type(2)));
typedef short bf16x8 __attribute__((ext_vector_type(8)));
typedef short bf16x16 __attribute__((ext_vector_type(16)));

static __device__ inline short f2bf(float f) {
    union { __hip_bfloat16 h; short s; } u;
    u.h = __float2bfloat16(f);
    return u.s;
}

static __device__ inline float bf2f(short s) {
    union { float f; unsigned u; } x;
    x.u = ((unsigned)(unsigned short)s) << 16;
    return x.f;
}

static __device__ inline float fast_rcp(float x) { return __builtin_amdgcn_rcpf(x); }

// Fused: blocks [0,1250) histogram dst; blocks [1250,1634) prepack all 5 weights.
// Pack order: out[((t*8+jt)*64+l)*8+b] = Wcat[32t + (l>>4)*8 + b][jt*16 + (l&15)]
__global__ void prep_hist(const float* __restrict__ W_sg, const float* __restrict__ W_tp,
                          const float* __restrict__ W_dg, const float* __restrict__ W_du,
                          const float* __restrict__ W_su, const float* __restrict__ W_eg,
                          short* __restrict__ Wsrc, short* __restrict__ Wdg,
                          short* __restrict__ Wdu, short* __restrict__ Wsu,
                          short* __restrict__ Weg,
                          const int* __restrict__ dst, int* __restrict__ cnt) {
    int bid = blockIdx.x;
    if (bid < 1250) {
        int i = bid * 256 + threadIdx.x;   // 1250*256 == N_EDGES exactly
        atomicAdd(&cnt[dst[i]], 1);
        return;
    }
    int idx = (bid - 1250) * 256 + threadIdx.x;
    const float* W0; const float* W1; short* out; int i2;
    if (idx < 32768)      { W0 = W_sg; W1 = W_tp; out = Wsrc; i2 = idx; }
    else if (idx < 49152) { W0 = W_dg; W1 = W_dg; out = Wdg;  i2 = idx - 32768; }
    else if (idx < 65536) { W0 = W_du; W1 = W_du; out = Wdu;  i2 = idx - 49152; }
    else if (idx < 81920) { W0 = W_su; W1 = W_su; out = Wsu;  i2 = idx - 65536; }
    else                  { W0 = W_eg; W1 = W_eg; out = Weg;  i2 = idx - 81920; }
    int b  = i2 & 7;
    int l  = (i2 >> 3) & 63;
    int jt = (i2 >> 9) & 7;
    int t  = i2 >> 12;
    int k = 32 * t + ((l >> 4) * 8) + b;
    int j = jt * 16 + (l & 15);
    float v = (k < 128) ? W0[k * 128 + j] : W1[(k - 128) * 128 + j];
    out[i2] = f2bf(v);
}

__launch_bounds__(1024)
__global__ void scan_kernel(const int* __restrict__ cnt, int* __restrict__ cursor) {
    __shared__ int s[1024];
    int t = threadIdx.x;
    int b0 = t * 10;
    int loc[10];
    int tot = 0;
#pragma unroll
    for (int i = 0; i < 10; ++i) {
        int v = (b0 + i < NBINS) ? cnt[b0 + i] : 0;
        loc[i] = tot; tot += v;
    }
    s[t] = tot;
    __syncthreads();
    for (int off = 1; off < 1024; off <<= 1) {
        int v = (t >= off) ? s[t - off] : 0;
        __syncthreads();
        s[t] += v;
        __syncthreads();
    }
    int base = (t == 0) ? 0 : s[t - 1];
#pragma unroll
    for (int i = 0; i < 10; ++i)
        if (b0 + i < NBINS) cursor[b0 + i] = base + loc[i];
}

__global__ void scatter_kernel(const int* __restrict__ src, const int* __restrict__ dst,
                               int* __restrict__ cursor,
                               int* __restrict__ perm,
                               int* __restrict__ src_s, int* __restrict__ dst_s) {
    int i = blockIdx.x * 256 + threadIdx.x;
    if (i < N_EDGES) {
        int d = dst[i];
        int p = atomicAdd(&cursor[d], 1);
        perm[p] = i;
        src_s[p] = src[i];
        dst_s[p] = d;
    }
}

// Unified: all four GEMMs per 64-row stripe; spk rows written as full 32B
// {es8|bh8} units (no partial-line interleave).
__launch_bounds__(256)
__global__ void node_proj_kernel(const float* __restrict__ node,
                                 const float* __restrict__ timef,
                                 const short* __restrict__ Wsrc_pk,  // K=256 (W_sg ; W_tp)
                                 const short* __restrict__ Wdg_pk,
                                 const short* __restrict__ Wdu_pk,
                                 const short* __restrict__ Wsu_pk,
                                 const float* __restrict__ b_sg, const float* __restrict__ b_tp,
                                 const float* __restrict__ b_dg, const float* __restrict__ b_du,
                                 const float* __restrict__ b_su, const float* __restrict__ b_eg,
                                 short* __restrict__ spk,   // [N][256] bf16: per-lane {es8|bh8}
                                 short* __restrict__ dpk,   // [N][128] bf16 col-permuted: e_dst
                                 float* __restrict__ xs) {
    int tid = threadIdx.x;
    int w = tid >> 6;
    int l = tid & 63;
    int g = l >> 4;
    int lr = l & 15;
    int r0 = blockIdx.x * 64 + w * 16;
    int arow = r0 + lr;

    bf16x8 aN[4], aT[4];
    if (arow < N_NODES) {
        const float* np = node + (size_t)arow * D;
        const float* tp = timef + (size_t)arow * D;
#pragma unroll
        for (int t = 0; t < 4; ++t) {
            int k0 = 32 * t + g * 8;
            f32x4 v0 = *(const f32x4*)(np + k0);
            f32x4 v1 = *(const f32x4*)(np + k0 + 4);
            f32x4 u0 = *(const f32x4*)(tp + k0);
            f32x4 u1 = *(const f32x4*)(tp + k0 + 4);
            bf16x8 a, b;
#pragma unroll
            for (int i = 0; i < 4; ++i) {
                a[i] = f2bf(v0[i]); a[4 + i] = f2bf(v1[i]);
                b[i] = f2bf(u0[i]); b[4 + i] = f2bf(u1[i]);
            }
            aN[t] = a; aT[t] = b;
        }
    } else {
        bf16x8 z = {0, 0, 0, 0, 0, 0, 0, 0};
#pragma unroll
        for (int t = 0; t < 4; ++t) { aN[t] = z; aT[t] = z; }
    }

    const bf16x8* Bsrc = (const bf16x8*)Wsrc_pk;
    const bf16x8* Bdg  = (const bf16x8*)Wdg_pk;
    const bf16x8* Bdu  = (const bf16x8*)Wdu_pk;
    const bf16x8* Bsu  = (const bf16x8*)Wsu_pk;

    // e_src = node@W_sg + time@W_tp + biases (K = 256); kept in regs until the
    // combined {es|bh} store below.
    bf16x8 chE[4];
#pragma unroll
    for (int jt = 0; jt < 8; ++jt) {
        int c = jt * 16 + lr;
        f32x4 acc = {0.f, 0.f, 0.f, 0.f};
#pragma unroll
        for (int t = 0; t < 4; ++t)
            acc = __builtin_amdgcn_mfma_f32_16x16x32_bf16(aN[t], Bsrc[(t * 8 + jt) * 64 + l], acc, 0, 0, 0);
#pragma unroll
        for (int t = 0; t < 4; ++t)
            acc = __builtin_amdgcn_mfma_f32_16x16x32_bf16(aT[t], Bsrc[((4 + t) * 8 + jt) * 64 + l], acc, 0, 0, 0);
        float bias = b_sg[c] + b_tp[c];
#pragma unroll
        for (int r = 0; r < 4; ++r) chE[r][jt] = f2bf(acc[r] + bias);
    }

    // e_dst (+b_dg+b_eg) -> dpk ; Bh (+b_du) joins chE in spk ; xs (+b_su) f32
    bf16x8 chD[4], chH[4];
    float xsv[4][8];
#pragma unroll
    for (int jt = 0; jt < 8; ++jt) {
        int c = jt * 16 + lr;
        f32x4 a0 = {0.f, 0.f, 0.f, 0.f}, a1 = a0, a2 = a0;
#pragma unroll
        for (int t = 0; t < 4; ++t) {
            a0 = __builtin_amdgcn_mfma_f32_16x16x32_bf16(aN[t], Bdg[(t * 8 + jt) * 64 + l], a0, 0, 0, 0);
            a1 = __builtin_amdgcn_mfma_f32_16x16x32_bf16(aN[t], Bdu[(t * 8 + jt) * 64 + l], a1, 0, 0, 0);
            a2 = __builtin_amdgcn_mfma_f32_16x16x32_bf16(aN[t], Bsu[(t * 8 + jt) * 64 + l], a2, 0, 0, 0);
        }
        float bdgc = b_dg[c] + b_eg[c];
        float bdu = b_du[c], bsu = b_su[c];
#pragma unroll
        for (int r = 0; r < 4; ++r) {
            chD[r][jt] = f2bf(a0[r] + bdgc);
            chH[r][jt] = f2bf(a1[r] + bdu);
            xsv[r][jt] = a2[r] + bsu;
        }
    }
#pragma unroll
    for (int r = 0; r < 4; ++r) {
        int row = r0 + g * 4 + r;
        if (row < N_NODES) {
            bf16x16 comb;
#pragma unroll
            for (int jt = 0; jt < 8; ++jt) { comb[jt] = chE[r][jt]; comb[8 + jt] = chH[r][jt]; }
            *(bf16x16*)(spk + (size_t)row * 256 + lr * 16) = comb;   // full 32B unit
            *(bf16x8*)(dpk + (size_t)row * D + lr * 8) = chD[r];
#pragma unroll
            for (int jt = 0; jt < 8; ++jt)
                xs[(size_t)row * D + jt * 16 + lr] = xsv[r][jt];
        }
    }
}

// ---- edge kernel: 2 tiles of 16 dst-sorted edges per wave (round-6 config) ----

#define TILE_LOAD_IDX(S, E0) \
    const int eA##S = perm[(E0) + lr]; \
    int eidx##S[4], sidx##S[4], didx##S[4]; \
    _Pragma("unroll") \
    for (int r = 0; r < 4; ++r) { \
        int p = (E0) + g * 4 + r; \
        eidx##S[r] = perm[p]; sidx##S[r] = src_s[p]; didx##S[r] = dst_s[p]; \
    } \
    const int df##S = __shfl(didx##S[0], 0); \
    const bool uni##S = (df##S == __shfl(didx##S[3], 48));

#define TILE_GATHER(S) \
    bf16x16 esbh##S[4]; bf16x8 edv##S[4]; \
    _Pragma("unroll") \
    for (int r = 0; r < 4; ++r) \
        esbh##S[r] = *(const bf16x16*)(spk + (size_t)sidx##S[r] * 256 + lr * 16); \
    edv##S[0] = *(const bf16x8*)(dpk + (size_t)didx##S[0] * D + lr * 8); \
    if (!uni##S) { \
        _Pragma("unroll") \
        for (int r = 1; r < 4; ++r) \
            edv##S[r] = *(const bf16x8*)(dpk + (size_t)didx##S[r] * D + lr * 8); \
    } else { edv##S[1] = edv##S[0]; edv##S[2] = edv##S[0]; edv##S[3] = edv##S[0]; }

#define TILE_AFRAG(S) \
    bf16x8 aE##S[4]; \
    { const float* ep = edgef + (size_t)eA##S * D; \
      _Pragma("unroll") \
      for (int t = 0; t < 4; ++t) { \
        int k0 = 32 * t + g * 8; \
        f32x4 v0 = *(const f32x4*)(ep + k0); \
        f32x4 v1 = *(const f32x4*)(ep + k0 + 4); \
        bf16x8 a; \
        _Pragma("unroll") \
        for (int i = 0; i < 4; ++i) { a[i] = f2bf(v0[i]); a[4 + i] = f2bf(v1[i]); } \
        aE##S[t] = a; } }

#define TILE_COMPUTE(S) \
    f32x4 acc##S[8]; \
    _Pragma("unroll") \
    for (int jt = 0; jt < 8; ++jt) { \
        f32x4 c4 = {0.f, 0.f, 0.f, 0.f}; \
        _Pragma("unroll") \
        for (int t = 0; t < 4; ++t) \
            c4 = __builtin_amdgcn_mfma_f32_16x16x32_bf16(aE##S[t], Bp[(t * 8 + jt) * 64 + l], c4, 0, 0, 0); \
        acc##S[jt] = c4; } \
    float sum##S[4] = {0.f, 0.f, 0.f, 0.f}, sq##S[4] = {0.f, 0.f, 0.f, 0.f}; \
    _Pragma("unroll") \
    for (int jt = 0; jt < 8; ++jt) { \
        int c = jt * 16 + lr; \
        float sg[4], bsg[4]; \
        _Pragma("unroll") \
        for (int r = 0; r < 4; ++r) { \
            float m = acc##S[jt][r] + bf2f(esbh##S[r][jt]) + bf2f(edv##S[r][jt]); \
            acc##S[jt][r] = m; \
            float s = fast_rcp(1.f + __expf(-m)); \
            sg[r] = s; bsg[r] = bf2f(esbh##S[r][8 + jt]) * s; \
            sum##S[r] += m; sq##S[r] += m * m; } \
        if (uni##S) { \
            float aS = (sg[0] + sg[1]) + (sg[2] + sg[3]); \
            float aH = (bsg[0] + bsg[1]) + (bsg[2] + bsg[3]); \
            aS += __shfl_xor(aS, 16); aH += __shfl_xor(aH, 16); \
            aS += __shfl_xor(aS, 32); aH += __shfl_xor(aH, 32); \
            if (g == 0) { \
                atomicAdd(&ss [(size_t)df##S * D + c], aS); \
                atomicAdd(&ssh[(size_t)df##S * D + c], aH); } \
        } else { \
            float aS = sg[0], aH = bsg[0]; \
            _Pragma("unroll") \
            for (int r = 1; r < 4; ++r) { \
                if (didx##S[r] == didx##S[r - 1]) { aS += sg[r]; aH += bsg[r]; } \
                else { \
                    atomicAdd(&ss [(size_t)didx##S[r - 1] * D + c], aS); \
                    atomicAdd(&ssh[(size_t)didx##S[r - 1] * D + c], aH); \
                    aS = sg[r]; aH = bsg[r]; } } \
            atomicAdd(&ss [(size_t)didx##S[3] * D + c], aS); \
            atomicAdd(&ssh[(size_t)didx##S[3] * D + c], aH); } }

#define TILE_EPILOGUE(S) \
    _Pragma("unroll") \
    for (int r = 0; r < 4; ++r) { \
        float s = sum##S[r], q = sq##S[r]; \
        _Pragma("unroll") \
        for (int mk = 1; mk < 16; mk <<= 1) { s += __shfl_xor(s, mk); q += __shfl_xor(q, mk); } \
        float mean = s * (1.f / D); \
        sum##S[r] = mean; \
        sq##S[r] = rsqrtf(q * (1.f / D) - mean * mean + 1e-5f); } \
    _Pragma("unroll") \
    for (int jt = 0; jt < 8; ++jt) { \
        int c = jt * 16 + lr; \
        float gc = ln_g[c], bc = ln_b[c]; \
        _Pragma("unroll") \
        for (int r = 0; r < 4; ++r) { \
            float v = (acc##S[jt][r] - sum##S[r]) * sq##S[r] * gc + bc; \
            float sl = v * fast_rcp(1.f + __expf(-v)); \
            size_t off = (size_t)eidx##S[r] * D + c; \
            y[off] = __builtin_nontemporal_load(&edgef[off]) + sl; } }

__launch_bounds__(256)
__global__ void edge_kernel(const float* __restrict__ edgef,
                            const int* __restrict__ perm,
                            const int* __restrict__ src_s, const int* __restrict__ dst_s,
                            const short* __restrict__ Weg_pk,
                            const short* __restrict__ spk,   // [N][256]: {es8|bh8} per lane
                            const short* __restrict__ dpk,   // [N][128]: e_dst
                            const float* __restrict__ ln_g, const float* __restrict__ ln_b,
                            float* __restrict__ ss, float* __restrict__ ssh,
                            float* __restrict__ y) {
    __shared__ short Bs[128 * 128];  // 32 KB: Weg B-fragments
    {
        const bf16x8* gw = (const bf16x8*)Weg_pk;
        bf16x8* sw = (bf16x8*)Bs;
        for (int i = threadIdx.x; i < 2048; i += 256) sw[i] = gw[i];
    }
    __syncthreads();

    int tid = threadIdx.x;
    int w = tid >> 6;
    int l = tid & 63;
    int g = l >> 4;
    int lr = l & 15;

    // bijective XCD-chunked swizzle over 2500 blocks (q=312, r=4)
    int b = blockIdx.x;
    int xcd = b & 7, boff = b >> 3;
    int swz = (xcd < 4 ? xcd * 313 : 1252 + (xcd - 4) * 312) + boff;
    int ebase = swz * 128 + w * 32;

    const bf16x8* Bp = (const bf16x8*)Bs;

    TILE_LOAD_IDX(0, ebase)
    TILE_LOAD_IDX(1, ebase + 16)
    TILE_GATHER(0)
    TILE_AFRAG(0)
    TILE_AFRAG(1)
    TILE_COMPUTE(0)
    TILE_GATHER(1)
    TILE_EPILOGUE(0)
    TILE_COMPUTE(1)
    TILE_EPILOGUE(1)
}

__launch_bounds__(256)
__global__ void node_out_kernel(const float* __restrict__ node,
                                const float* __restrict__ xs,
                                const float* __restrict__ ssh, const float* __restrict__ ss,
                                const float* __restrict__ ln_g, const float* __restrict__ ln_b,
                                float* __restrict__ x) {
    int w = threadIdx.x >> 6;
    int l = threadIdx.x & 63;
    int row = blockIdx.x * 4 + w;
    if (row >= N_NODES) return;
    size_t base = (size_t)row * D + 2 * l;
    f32x2 xv = *(const f32x2*)(xs + base);
    f32x2 hs = *(const f32x2*)(ssh + base);
    f32x2 sv = *(const f32x2*)(ss + base);
    float v0 = xv[0] + hs[0] / (sv[0] + 1e-6f);
    float v1 = xv[1] + hs[1] / (sv[1] + 1e-6f);
    float s = v0 + v1, q = v0 * v0 + v1 * v1;
#pragma unroll
    for (int mk = 1; mk < 64; mk <<= 1) { s += __shfl_xor(s, mk); q += __shfl_xor(q, mk); }
    float mean = s * (1.f / D);
    float var = q * (1.f / D) - mean * mean;
    float rstd = rsqrtf(var + 1e-5f);
    float t0 = (v0 - mean) * rstd * ln_g[2 * l] + ln_b[2 * l];
    float t1 = (v1 - mean) * rstd * ln_g[2 * l + 1] + ln_b[2 * l + 1];
    t0 = t0 * fast_rcp(1.f + __expf(-t0));
    t1 = t1 * fast_rcp(1.f + __expf(-t1));
    f32x2 nv = *(const f32x2*)(node + base);
    f32x2 outv;
    outv[0] = nv[0] + t0;
    outv[1] = nv[1] + t1;
    *(f32x2*)(x + base) = outv;
}

extern "C" void kernel_launch(void* const* d_in, const int* in_sizes, int n_in,
                              void* d_out, int out_size, void* d_ws, size_t ws_size,
                              hipStream_t stream) {
    const float* node  = (const float*)d_in[0];
    const float* edgef = (const float*)d_in[1];
    const float* timef = (const float*)d_in[2];
    const int*   src   = (const int*)d_in[3];
    const int*   dst   = (const int*)d_in[4];
    const float* W_tp = (const float*)d_in[5];  const float* b_tp = (const float*)d_in[6];
    const float* W_sg = (const float*)d_in[7];  const float* b_sg = (const float*)d_in[8];
    const float* W_dg = (const float*)d_in[9];  const float* b_dg = (const float*)d_in[10];
    const float* W_eg = (const float*)d_in[11]; const float* b_eg = (const float*)d_in[12];
    const float* W_su = (const float*)d_in[13]; const float* b_su = (const float*)d_in[14];
    const float* W_du = (const float*)d_in[15]; const float* b_du = (const float*)d_in[16];
    const float* ln_e_g = (const float*)d_in[17]; const float* ln_e_b = (const float*)d_in[18];
    const float* ln_n_g = (const float*)d_in[19]; const float* ln_n_b = (const float*)d_in[20];

    char* ws = (char*)d_ws;
    size_t nd = (size_t)N_NODES * D;
    // cnt | cursor | ss | ssh contiguous -> single memset clears all
    int* cnt       = (int*)ws; ws += 10240 * 4;
    int* cursor    = (int*)ws; ws += 10240 * 4;
    float* ss    = (float*)ws; ws += nd * 4;
    float* ssh   = (float*)ws; ws += nd * 4;
    float* xs    = (float*)ws; ws += nd * 4;
    short* spk   = (short*)ws; ws += (size_t)N_NODES * 256 * 2;
    short* dpk   = (short*)ws; ws += nd * 2;
    short* Wsrc_pk = (short*)ws; ws += 256 * 128 * 2;
    short* Wdg_pk  = (short*)ws; ws += 128 * 128 * 2;
    short* Wdu_pk  = (short*)ws; ws += 128 * 128 * 2;
    short* Wsu_pk  = (short*)ws; ws += 128 * 128 * 2;
    short* Weg_pk  = (short*)ws; ws += 128 * 128 * 2;
    int* perm      = (int*)ws; ws += (size_t)N_EDGES * 4;
    int* src_s     = (int*)ws; ws += (size_t)N_EDGES * 4;
    int* dst_s     = (int*)ws; ws += (size_t)N_EDGES * 4;

    hipMemsetAsync(cnt, 0, 2 * 10240 * 4 + 2 * nd * 4, stream);

    // fused prepack + histogram
    prep_hist<<<1634, 256, 0, stream>>>(W_sg, W_tp, W_dg, W_du, W_su, W_eg,
                                        Wsrc_pk, Wdg_pk, Wdu_pk, Wsu_pk, Weg_pk,
                                        dst, cnt);
    scan_kernel<<<1, 1024, 0, stream>>>(cnt, cursor);
    scatter_kernel<<<(N_EDGES + 255) / 256, 256, 0, stream>>>(src, dst, cursor, perm, src_s, dst_s);

    node_proj_kernel<<<(N_NODES + 63) / 64, 256, 0, stream>>>(
        node, timef, Wsrc_pk, Wdg_pk, Wdu_pk, Wsu_pk,
        b_sg, b_tp, b_dg, b_du, b_su, b_eg, spk, dpk, xs);

    edge_kernel<<<2500, 256, 0, stream>>>(
        edgef, perm, src_s, dst_s, Weg_pk, spk, dpk,
        ln_e_g, ln_e_b, ss, ssh, (float*)d_out + nd);

    node_out_kernel<<<N_NODES / 4, 256, 0, stream>>>(
        node, xs, ssh, ss, ln_n_g, ln_n_b, (float*)d_out);
}

// Round 10
// 250.767 us; speedup vs baseline: 2.3176x; 1.0793x over previous
//
#include <hip/hip_runtime.h>
#include <hip/hip_bf16.h>

#define N_NODES 10000
#define N_EDGES 320000
#define D 128
#define NBINS 10000

typedef float f32x4 __attribute__((ext_vector_type(4)));
typedef float f32x2 __attribute__((ext_vector_type(2)));
typedef short bf16x8 __attribute__((ext_vector_type(8)));
typedef short bf16x16 __attribute__((ext_vector_type(16)));

static __device__ inline short f2bf(float f) {
    union { __hip_bfloat16 h; short s; } u;
    u.h = __float2bfloat16(f);
    return u.s;
}

static __device__ inline float bf2f(short s) {
    union { float f; unsigned u; } x;
    x.u = ((unsigned)(unsigned short)s) << 16;
    return x.f;
}

static __device__ inline float fast_rcp(float x) { return __builtin_amdgcn_rcpf(x); }

// All 5 weight packs in one launch (384 blocks).
// Pack order: out[((t*8+jt)*64+l)*8+b] = Wcat[32t + (l>>4)*8 + b][jt*16 + (l&15)]
__global__ void prepack_all(const float* __restrict__ W_sg, const float* __restrict__ W_tp,
                            const float* __restrict__ W_dg, const float* __restrict__ W_du,
                            const float* __restrict__ W_su, const float* __restrict__ W_eg,
                            short* __restrict__ Wsrc, short* __restrict__ Wdg,
                            short* __restrict__ Wdu, short* __restrict__ Wsu,
                            short* __restrict__ Weg) {
    int idx = blockIdx.x * 256 + threadIdx.x;
    const float* W0; const float* W1; short* out; int i2;
    if (idx < 32768)      { W0 = W_sg; W1 = W_tp; out = Wsrc; i2 = idx; }
    else if (idx < 49152) { W0 = W_dg; W1 = W_dg; out = Wdg;  i2 = idx - 32768; }
    else if (idx < 65536) { W0 = W_du; W1 = W_du; out = Wdu;  i2 = idx - 49152; }
    else if (idx < 81920) { W0 = W_su; W1 = W_su; out = Wsu;  i2 = idx - 65536; }
    else                  { W0 = W_eg; W1 = W_eg; out = Weg;  i2 = idx - 81920; }
    int b  = i2 & 7;
    int l  = (i2 >> 3) & 63;
    int jt = (i2 >> 9) & 7;
    int t  = i2 >> 12;
    int k = 32 * t + ((l >> 4) * 8) + b;
    int j = jt * 16 + (l & 15);
    float v = (k < 128) ? W0[k * 128 + j] : W1[(k - 128) * 128 + j];
    out[i2] = f2bf(v);
}

__global__ void hist_kernel(const int* __restrict__ dst, int* __restrict__ cnt) {
    int i = blockIdx.x * 256 + threadIdx.x;
    if (i < N_EDGES) atomicAdd(&cnt[dst[i]], 1);
}

__launch_bounds__(1024)
__global__ void scan_kernel(const int* __restrict__ cnt, int* __restrict__ cursor) {
    __shared__ int s[1024];
    int t = threadIdx.x;
    int b0 = t * 10;
    int loc[10];
    int tot = 0;
#pragma unroll
    for (int i = 0; i < 10; ++i) {
        int v = (b0 + i < NBINS) ? cnt[b0 + i] : 0;
        loc[i] = tot; tot += v;
    }
    s[t] = tot;
    __syncthreads();
    for (int off = 1; off < 1024; off <<= 1) {
        int v = (t >= off) ? s[t - off] : 0;
        __syncthreads();
        s[t] += v;
        __syncthreads();
    }
    int base = (t == 0) ? 0 : s[t - 1];
#pragma unroll
    for (int i = 0; i < 10; ++i)
        if (b0 + i < NBINS) cursor[b0 + i] = base + loc[i];
}

// Fused: blocks [0,1250) scatter (sort emit); blocks [1250,1407) node projections.
// Both depend only on scan + prepack, so they overlap in one dispatch.
__launch_bounds__(256)
__global__ void scatter_proj_kernel(const int* __restrict__ src, const int* __restrict__ dst,
                                    int* __restrict__ cursor,
                                    int* __restrict__ perm,
                                    int* __restrict__ src_s, int* __restrict__ dst_s,
                                    const float* __restrict__ node,
                                    const float* __restrict__ timef,
                                    const short* __restrict__ Wsrc_pk,
                                    const short* __restrict__ Wdg_pk,
                                    const short* __restrict__ Wdu_pk,
                                    const short* __restrict__ Wsu_pk,
                                    const float* __restrict__ b_sg, const float* __restrict__ b_tp,
                                    const float* __restrict__ b_dg, const float* __restrict__ b_du,
                                    const float* __restrict__ b_su, const float* __restrict__ b_eg,
                                    short* __restrict__ spk,   // [N][256] bf16: per-lane {es8|bh8}
                                    short* __restrict__ dpk,   // [N][128] bf16: e_dst
                                    float* __restrict__ xs) {
    if (blockIdx.x < 1250) {
        int i = blockIdx.x * 256 + threadIdx.x;   // 1250*256 == N_EDGES
        int d = dst[i];
        int p = atomicAdd(&cursor[d], 1);
        perm[p] = i;
        src_s[p] = src[i];
        dst_s[p] = d;
        return;
    }

    int tid = threadIdx.x;
    int w = tid >> 6;
    int l = tid & 63;
    int g = l >> 4;
    int lr = l & 15;
    int r0 = (blockIdx.x - 1250) * 64 + w * 16;
    int arow = r0 + lr;

    bf16x8 aN[4], aT[4];
    if (arow < N_NODES) {
        const float* np = node + (size_t)arow * D;
        const float* tp = timef + (size_t)arow * D;
#pragma unroll
        for (int t = 0; t < 4; ++t) {
            int k0 = 32 * t + g * 8;
            f32x4 v0 = *(const f32x4*)(np + k0);
            f32x4 v1 = *(const f32x4*)(np + k0 + 4);
            f32x4 u0 = *(const f32x4*)(tp + k0);
            f32x4 u1 = *(const f32x4*)(tp + k0 + 4);
            bf16x8 a, b;
#pragma unroll
            for (int i = 0; i < 4; ++i) {
                a[i] = f2bf(v0[i]); a[4 + i] = f2bf(v1[i]);
                b[i] = f2bf(u0[i]); b[4 + i] = f2bf(u1[i]);
            }
            aN[t] = a; aT[t] = b;
        }
    } else {
        bf16x8 z = {0, 0, 0, 0, 0, 0, 0, 0};
#pragma unroll
        for (int t = 0; t < 4; ++t) { aN[t] = z; aT[t] = z; }
    }

    const bf16x8* Bsrc = (const bf16x8*)Wsrc_pk;
    const bf16x8* Bdg  = (const bf16x8*)Wdg_pk;
    const bf16x8* Bdu  = (const bf16x8*)Wdu_pk;
    const bf16x8* Bsu  = (const bf16x8*)Wsu_pk;

    // e_src (K=256): store each row's 16B es-half immediately (low reg pressure;
    // the bh-half of the same 32B unit is written by this same wave below).
    {
        bf16x8 chunk[4];
#pragma unroll
        for (int jt = 0; jt < 8; ++jt) {
            int c = jt * 16 + lr;
            f32x4 acc = {0.f, 0.f, 0.f, 0.f};
#pragma unroll
            for (int t = 0; t < 4; ++t)
                acc = __builtin_amdgcn_mfma_f32_16x16x32_bf16(aN[t], Bsrc[(t * 8 + jt) * 64 + l], acc, 0, 0, 0);
#pragma unroll
            for (int t = 0; t < 4; ++t)
                acc = __builtin_amdgcn_mfma_f32_16x16x32_bf16(aT[t], Bsrc[((4 + t) * 8 + jt) * 64 + l], acc, 0, 0, 0);
            float bias = b_sg[c] + b_tp[c];
#pragma unroll
            for (int r = 0; r < 4; ++r) chunk[r][jt] = f2bf(acc[r] + bias);
        }
#pragma unroll
        for (int r = 0; r < 4; ++r) {
            int row = r0 + g * 4 + r;
            if (row < N_NODES) *(bf16x8*)(spk + (size_t)row * 256 + lr * 16) = chunk[r];
        }
    }

    // e_dst (+b_dg+b_eg) -> dpk ; Bh (+b_du) -> spk second 16B half ; xs (+b_su)
    {
        bf16x8 chD[4], chH[4];
        float xsv[4][8];
#pragma unroll
        for (int jt = 0; jt < 8; ++jt) {
            int c = jt * 16 + lr;
            f32x4 a0 = {0.f, 0.f, 0.f, 0.f}, a1 = a0, a2 = a0;
#pragma unroll
            for (int t = 0; t < 4; ++t) {
                a0 = __builtin_amdgcn_mfma_f32_16x16x32_bf16(aN[t], Bdg[(t * 8 + jt) * 64 + l], a0, 0, 0, 0);
                a1 = __builtin_amdgcn_mfma_f32_16x16x32_bf16(aN[t], Bdu[(t * 8 + jt) * 64 + l], a1, 0, 0, 0);
                a2 = __builtin_amdgcn_mfma_f32_16x16x32_bf16(aN[t], Bsu[(t * 8 + jt) * 64 + l], a2, 0, 0, 0);
            }
            float bdgc = b_dg[c] + b_eg[c];
            float bdu = b_du[c], bsu = b_su[c];
#pragma unroll
            for (int r = 0; r < 4; ++r) {
                chD[r][jt] = f2bf(a0[r] + bdgc);
                chH[r][jt] = f2bf(a1[r] + bdu);
                xsv[r][jt] = a2[r] + bsu;
            }
        }
#pragma unroll
        for (int r = 0; r < 4; ++r) {
            int row = r0 + g * 4 + r;
            if (row < N_NODES) {
                *(bf16x8*)(dpk + (size_t)row * D + lr * 8) = chD[r];
                *(bf16x8*)(spk + (size_t)row * 256 + lr * 16 + 8) = chH[r];
#pragma unroll
                for (int jt = 0; jt < 8; ++jt)
                    xs[(size_t)row * D + jt * 16 + lr] = xsv[r][jt];
            }
        }
    }
}

// ---- edge kernel: 2 tiles of 16 dst-sorted edges per wave (frozen: r9 config) ----

#define TILE_LOAD_IDX(S, E0) \
    const int eA##S = perm[(E0) + lr]; \
    int eidx##S[4], sidx##S[4], didx##S[4]; \
    _Pragma("unroll") \
    for (int r = 0; r < 4; ++r) { \
        int p = (E0) + g * 4 + r; \
        eidx##S[r] = perm[p]; sidx##S[r] = src_s[p]; didx##S[r] = dst_s[p]; \
    } \
    const int df##S = __shfl(didx##S[0], 0); \
    const bool uni##S = (df##S == __shfl(didx##S[3], 48));

#define TILE_GATHER(S) \
    bf16x16 esbh##S[4]; bf16x8 edv##S[4]; \
    _Pragma("unroll") \
    for (int r = 0; r < 4; ++r) \
        esbh##S[r] = *(const bf16x16*)(spk + (size_t)sidx##S[r] * 256 + lr * 16); \
    edv##S[0] = *(const bf16x8*)(dpk + (size_t)didx##S[0] * D + lr * 8); \
    if (!uni##S) { \
        _Pragma("unroll") \
        for (int r = 1; r < 4; ++r) \
            edv##S[r] = *(const bf16x8*)(dpk + (size_t)didx##S[r] * D + lr * 8); \
    } else { edv##S[1] = edv##S[0]; edv##S[2] = edv##S[0]; edv##S[3] = edv##S[0]; }

#define TILE_AFRAG(S) \
    bf16x8 aE##S[4]; \
    { const float* ep = edgef + (size_t)eA##S * D; \
      _Pragma("unroll") \
      for (int t = 0; t < 4; ++t) { \
        int k0 = 32 * t + g * 8; \
        f32x4 v0 = *(const f32x4*)(ep + k0); \
        f32x4 v1 = *(const f32x4*)(ep + k0 + 4); \
        bf16x8 a; \
        _Pragma("unroll") \
        for (int i = 0; i < 4; ++i) { a[i] = f2bf(v0[i]); a[4 + i] = f2bf(v1[i]); } \
        aE##S[t] = a; } }

#define TILE_COMPUTE(S) \
    f32x4 acc##S[8]; \
    _Pragma("unroll") \
    for (int jt = 0; jt < 8; ++jt) { \
        f32x4 c4 = {0.f, 0.f, 0.f, 0.f}; \
        _Pragma("unroll") \
        for (int t = 0; t < 4; ++t) \
            c4 = __builtin_amdgcn_mfma_f32_16x16x32_bf16(aE##S[t], Bp[(t * 8 + jt) * 64 + l], c4, 0, 0, 0); \
        acc##S[jt] = c4; } \
    float sum##S[4] = {0.f, 0.f, 0.f, 0.f}, sq##S[4] = {0.f, 0.f, 0.f, 0.f}; \
    _Pragma("unroll") \
    for (int jt = 0; jt < 8; ++jt) { \
        int c = jt * 16 + lr; \
        float sg[4], bsg[4]; \
        _Pragma("unroll") \
        for (int r = 0; r < 4; ++r) { \
            float m = acc##S[jt][r] + bf2f(esbh##S[r][jt]) + bf2f(edv##S[r][jt]); \
            acc##S[jt][r] = m; \
            float s = fast_rcp(1.f + __expf(-m)); \
            sg[r] = s; bsg[r] = bf2f(esbh##S[r][8 + jt]) * s; \
            sum##S[r] += m; sq##S[r] += m * m; } \
        if (uni##S) { \
            float aS = (sg[0] + sg[1]) + (sg[2] + sg[3]); \
            float aH = (bsg[0] + bsg[1]) + (bsg[2] + bsg[3]); \
            aS += __shfl_xor(aS, 16); aH += __shfl_xor(aH, 16); \
            aS += __shfl_xor(aS, 32); aH += __shfl_xor(aH, 32); \
            if (g == 0) { \
                atomicAdd(&ss [(size_t)df##S * D + c], aS); \
                atomicAdd(&ssh[(size_t)df##S * D + c], aH); } \
        } else { \
            float aS = sg[0], aH = bsg[0]; \
            _Pragma("unroll") \
            for (int r = 1; r < 4; ++r) { \
                if (didx##S[r] == didx##S[r - 1]) { aS += sg[r]; aH += bsg[r]; } \
                else { \
                    atomicAdd(&ss [(size_t)didx##S[r - 1] * D + c], aS); \
                    atomicAdd(&ssh[(size_t)didx##S[r - 1] * D + c], aH); \
                    aS = sg[r]; aH = bsg[r]; } } \
            atomicAdd(&ss [(size_t)didx##S[3] * D + c], aS); \
            atomicAdd(&ssh[(size_t)didx##S[3] * D + c], aH); } }

#define TILE_EPILOGUE(S) \
    _Pragma("unroll") \
    for (int r = 0; r < 4; ++r) { \
        float s = sum##S[r], q = sq##S[r]; \
        _Pragma("unroll") \
        for (int mk = 1; mk < 16; mk <<= 1) { s += __shfl_xor(s, mk); q += __shfl_xor(q, mk); } \
        float mean = s * (1.f / D); \
        sum##S[r] = mean; \
        sq##S[r] = rsqrtf(q * (1.f / D) - mean * mean + 1e-5f); } \
    _Pragma("unroll") \
    for (int jt = 0; jt < 8; ++jt) { \
        int c = jt * 16 + lr; \
        float gc = ln_g[c], bc = ln_b[c]; \
        _Pragma("unroll") \
        for (int r = 0; r < 4; ++r) { \
            float v = (acc##S[jt][r] - sum##S[r]) * sq##S[r] * gc + bc; \
            float sl = v * fast_rcp(1.f + __expf(-v)); \
            size_t off = (size_t)eidx##S[r] * D + c; \
            y[off] = __builtin_nontemporal_load(&edgef[off]) + sl; } }

__launch_bounds__(256)
__global__ void edge_kernel(const float* __restrict__ edgef,
                            const int* __restrict__ perm,
                            const int* __restrict__ src_s, const int* __restrict__ dst_s,
                            const short* __restrict__ Weg_pk,
                            const short* __restrict__ spk,   // [N][256]: {es8|bh8} per lane
                            const short* __restrict__ dpk,   // [N][128]: e_dst
                            const float* __restrict__ ln_g, const float* __restrict__ ln_b,
                            float* __restrict__ ss, float* __restrict__ ssh,
                            float* __restrict__ y) {
    __shared__ short Bs[128 * 128];  // 32 KB: Weg B-fragments
    {
        const bf16x8* gw = (const bf16x8*)Weg_pk;
        bf16x8* sw = (bf16x8*)Bs;
        for (int i = threadIdx.x; i < 2048; i += 256) sw[i] = gw[i];
    }
    __syncthreads();

    int tid = threadIdx.x;
    int w = tid >> 6;
    int l = tid & 63;
    int g = l >> 4;
    int lr = l & 15;

    // bijective XCD-chunked swizzle over 2500 blocks (q=312, r=4)
    int b = blockIdx.x;
    int xcd = b & 7, boff = b >> 3;
    int swz = (xcd < 4 ? xcd * 313 : 1252 + (xcd - 4) * 312) + boff;
    int ebase = swz * 128 + w * 32;

    const bf16x8* Bp = (const bf16x8*)Bs;

    TILE_LOAD_IDX(0, ebase)
    TILE_LOAD_IDX(1, ebase + 16)
    TILE_GATHER(0)
    TILE_AFRAG(0)
    TILE_AFRAG(1)
    TILE_COMPUTE(0)
    TILE_GATHER(1)
    TILE_EPILOGUE(0)
    TILE_COMPUTE(1)
    TILE_EPILOGUE(1)
}

__launch_bounds__(256)
__global__ void node_out_kernel(const float* __restrict__ node,
                                const float* __restrict__ xs,
                                const float* __restrict__ ssh, const float* __restrict__ ss,
                                const float* __restrict__ ln_g, const float* __restrict__ ln_b,
                                float* __restrict__ x) {
    int w = threadIdx.x >> 6;
    int l = threadIdx.x & 63;
    int row = blockIdx.x * 4 + w;
    if (row >= N_NODES) return;
    size_t base = (size_t)row * D + 2 * l;
    f32x2 xv = *(const f32x2*)(xs + base);
    f32x2 hs = *(const f32x2*)(ssh + base);
    f32x2 sv = *(const f32x2*)(ss + base);
    float v0 = xv[0] + hs[0] / (sv[0] + 1e-6f);
    float v1 = xv[1] + hs[1] / (sv[1] + 1e-6f);
    float s = v0 + v1, q = v0 * v0 + v1 * v1;
#pragma unroll
    for (int mk = 1; mk < 64; mk <<= 1) { s += __shfl_xor(s, mk); q += __shfl_xor(q, mk); }
    float mean = s * (1.f / D);
    float var = q * (1.f / D) - mean * mean;
    float rstd = rsqrtf(var + 1e-5f);
    float t0 = (v0 - mean) * rstd * ln_g[2 * l] + ln_b[2 * l];
    float t1 = (v1 - mean) * rstd * ln_g[2 * l + 1] + ln_b[2 * l + 1];
    t0 = t0 * fast_rcp(1.f + __expf(-t0));
    t1 = t1 * fast_rcp(1.f + __expf(-t1));
    f32x2 nv = *(const f32x2*)(node + base);
    f32x2 outv;
    outv[0] = nv[0] + t0;
    outv[1] = nv[1] + t1;
    *(f32x2*)(x + base) = outv;
}

extern "C" void kernel_launch(void* const* d_in, const int* in_sizes, int n_in,
                              void* d_out, int out_size, void* d_ws, size_t ws_size,
                              hipStream_t stream) {
    const float* node  = (const float*)d_in[0];
    const float* edgef = (const float*)d_in[1];
    const float* timef = (const float*)d_in[2];
    const int*   src   = (const int*)d_in[3];
    const int*   dst   = (const int*)d_in[4];
    const float* W_tp = (const float*)d_in[5];  const float* b_tp = (const float*)d_in[6];
    const float* W_sg = (const float*)d_in[7];  const float* b_sg = (const float*)d_in[8];
    const float* W_dg = (const float*)d_in[9];  const float* b_dg = (const float*)d_in[10];
    const float* W_eg = (const float*)d_in[11]; const float* b_eg = (const float*)d_in[12];
    const float* W_su = (const float*)d_in[13]; const float* b_su = (const float*)d_in[14];
    const float* W_du = (const float*)d_in[15]; const float* b_du = (const float*)d_in[16];
    const float* ln_e_g = (const float*)d_in[17]; const float* ln_e_b = (const float*)d_in[18];
    const float* ln_n_g = (const float*)d_in[19]; const float* ln_n_b = (const float*)d_in[20];

    char* ws = (char*)d_ws;
    size_t nd = (size_t)N_NODES * D;
    // cnt | cursor | ss | ssh contiguous -> single memset clears all
    int* cnt       = (int*)ws; ws += 10240 * 4;
    int* cursor    = (int*)ws; ws += 10240 * 4;
    float* ss    = (float*)ws; ws += nd * 4;
    float* ssh   = (float*)ws; ws += nd * 4;
    float* xs    = (float*)ws; ws += nd * 4;
    short* spk   = (short*)ws; ws += (size_t)N_NODES * 256 * 2;
    short* dpk   = (short*)ws; ws += nd * 2;
    short* Wsrc_pk = (short*)ws; ws += 256 * 128 * 2;
    short* Wdg_pk  = (short*)ws; ws += 128 * 128 * 2;
    short* Wdu_pk  = (short*)ws; ws += 128 * 128 * 2;
    short* Wsu_pk  = (short*)ws; ws += 128 * 128 * 2;
    short* Weg_pk  = (short*)ws; ws += 128 * 128 * 2;
    int* perm      = (int*)ws; ws += (size_t)N_EDGES * 4;
    int* src_s     = (int*)ws; ws += (size_t)N_EDGES * 4;
    int* dst_s     = (int*)ws; ws += (size_t)N_EDGES * 4;

    hipMemsetAsync(cnt, 0, 2 * 10240 * 4 + 2 * nd * 4, stream);

    prepack_all<<<384, 256, 0, stream>>>(W_sg, W_tp, W_dg, W_du, W_su, W_eg,
                                         Wsrc_pk, Wdg_pk, Wdu_pk, Wsu_pk, Weg_pk);
    hist_kernel<<<1250, 256, 0, stream>>>(dst, cnt);
    scan_kernel<<<1, 1024, 0, stream>>>(cnt, cursor);

    // scatter (blocks 0-1249) overlapped with node projections (blocks 1250-1406)
    scatter_proj_kernel<<<1407, 256, 0, stream>>>(
        src, dst, cursor, perm, src_s, dst_s,
        node, timef, Wsrc_pk, Wdg_pk, Wdu_pk, Wsu_pk,
        b_sg, b_tp, b_dg, b_du, b_su, b_eg, spk, dpk, xs);

    edge_kernel<<<2500, 256, 0, stream>>>(
        edgef, perm, src_s, dst_s, Weg_pk, spk, dpk,
        ln_e_g, ln_e_b, ss, ssh, (float*)d_out + nd);

    node_out_kernel<<<N_NODES / 4, 256, 0, stream>>>(
        node, xs, ssh, ss, ln_n_g, ln_n_b, (float*)d_out);
}